// Round 1
// baseline (317.500 us; speedup 1.0000x reference)
//
#include <hip/hip_runtime.h>

typedef __attribute__((ext_vector_type(4))) float f32x4;
typedef __attribute__((ext_vector_type(8))) short bf16x8;
typedef __attribute__((ext_vector_type(4))) short bf16x4;

#define MFMA16(a, b, c) __builtin_amdgcn_mfma_f32_16x16x32_bf16(a, b, c, 0, 0, 0)

// ws fragment offsets in shorts (bf16 elements)
#define W1F_OFF 0        // 16384 elems (M=256,K=64,  KT=2)
#define W2F_OFF 16384    // 65536 elems (M=256,K=256, KT=8)
#define CF_OFF  81920    // 65536 elems (M=256,K=256, KT=8)
#define W3F_OFF 147456   // 16384 elems (M=64, K=256, KT=8)
// total 163840 shorts = 327680 bytes of d_ws

__device__ __forceinline__ short f2bf(float f) {
  unsigned u = __builtin_bit_cast(unsigned, f);
  u += 0x7FFFu + ((u >> 16) & 1u);          // RTNE (finite values only)
  return (short)(u >> 16);
}

__device__ __forceinline__ void sp_sig(float z, float& h, float& s) {
  // softplus + sigmoid sharing one exp:  t = e^{-|z|}
  float t = __expf(-fabsf(z));
#if __has_builtin(__builtin_amdgcn_rcpf)
  float r = __builtin_amdgcn_rcpf(1.f + t);
#else
  float r = 1.f / (1.f + t);
#endif
  h = fmaxf(z, 0.f) + __logf(1.f + t);      // log1p(t) fine at this tolerance
  s = (z >= 0.f) ? r : 1.f - r;
}

// ---------------------------------------------------------------------------
// Prep: swizzle W1, W2, C = W2 .* (W1@W3)^T, W3 into MFMA A-fragment order.
// Fragment element index: e = ((mt*KT + kt)*64 + lane)*8 + j
// A[m][k] with m = mt*16 + (lane&15), k = kt*32 + (lane>>4)*8 + j
// ---------------------------------------------------------------------------
__global__ __launch_bounds__(512) void cnf_prep(const float* __restrict__ W1,
                                                const float* __restrict__ W2,
                                                const float* __restrict__ W3,
                                                short* __restrict__ ws) {
  int e = blockIdx.x * 512 + threadIdx.x;   // [0, 163840)
  int j = e & 7;
  int l = (e >> 3) & 63;
  int g = l >> 4, lm = l & 15;
  float val;
  if (e < 16384) {                          // W1 frag: [256 x 64]
    int t = e >> 9, kt = t & 1, mt = t >> 1;
    val = W1[(mt * 16 + lm) * 64 + kt * 32 + g * 8 + j];
  } else if (e < 81920) {                   // W2 frag: [256 x 256]
    int t = (e - 16384) >> 9, kt = t & 7, mt = t >> 3;
    val = W2[(mt * 16 + lm) * 256 + kt * 32 + g * 8 + j];
  } else if (e < 147456) {                  // C frag: C[m][k] = W2[m,k]*A2[k,m]
    int t = (e - 81920) >> 9, kt = t & 7, mt = t >> 3;
    int m = mt * 16 + lm, k = kt * 32 + g * 8 + j;
    float a2 = 0.f;
#pragma unroll 16
    for (int d = 0; d < 64; ++d) a2 += W1[k * 64 + d] * W3[d * 256 + m];
    val = W2[m * 256 + k] * a2;
  } else {                                  // W3 frag: [64 x 256]
    int t = (e - 147456) >> 9, kt = t & 7, mt = t >> 3;
    val = W3[(mt * 16 + lm) * 256 + kt * 32 + g * 8 + j];
  }
  ws[e] = f2bf(val);
}

// ---------------------------------------------------------------------------
// Main: 256 blocks x 512 threads. Block b integrates samples [32b, 32b+32)
// through all 10 Dopri5 steps. Per dyn(): 4 bf16 MFMA GEMMs
//   z1^T[256x32] = W1 * ytmp^T ; z2^T = W2 * h1^T ; u^T = C * s1^T ; dy^T = W3 * h2^T
// Weights are A-operand fragments; activations are B-operands in LDS.
// ---------------------------------------------------------------------------
__global__ __launch_bounds__(512) void cnf_main(
    const float* __restrict__ x, const float* __restrict__ ld_init,
    const float* __restrict__ b1g, const float* __restrict__ b2g,
    const float* __restrict__ b3g, const float* __restrict__ Tg,
    const short* __restrict__ ws, float* __restrict__ outy,
    float* __restrict__ outl) {
  __shared__ __align__(16) short w1f[16384];       // 32 KB persistent W1 frags
  __shared__ __align__(16) short w3f[16384];       // 32 KB persistent W3 frags
  __shared__ __align__(16) short ytL[32 * 88];     // stage input, bf16 [s][d], stride 88
  __shared__ __align__(16) short h1L[32 * 264];    // softplus(z1), stride 264
  __shared__ __align__(16) short s1L_[32 * 264];   // sigmoid(z1)
  __shared__ __align__(16) short h2L[32 * 264];    // softplus(z2)
  __shared__ __align__(16) float dyL[32 * 68];     // dy f32 [s][d], stride 68
  __shared__ float trP[8][32];                     // per-wave trace partials
  __shared__ float b1L[256], b2L[256], b3L[64];

  const int tid = threadIdx.x;
  const int lane = tid & 63, wv = tid >> 6;        // 8 waves
  const int sl = tid >> 4, q = tid & 15;           // sample-local [0,32), d-chunk [0,16)
  const int lg = lane >> 4, lm = lane & 15;
  const int ko8 = lg << 3;

  // Stage persistent weights + biases into LDS
  {
    const f32x4* s1p = (const f32x4*)ws;                   // W1 frags
    f32x4* d1 = (f32x4*)w1f;
#pragma unroll
    for (int i = 0; i < 4; ++i) d1[tid + 512 * i] = s1p[tid + 512 * i];
    const f32x4* s3p = (const f32x4*)(ws + W3F_OFF);       // W3 frags
    f32x4* d3 = (f32x4*)w3f;
#pragma unroll
    for (int i = 0; i < 4; ++i) d3[tid + 512 * i] = s3p[tid + 512 * i];
    if (tid < 256) { b1L[tid] = b1g[tid]; b2L[tid] = b2g[tid]; }
    else if (tid < 320) b3L[tid - 256] = b3g[tid - 256];
  }

  const bf16x8* w2fG = (const bf16x8*)(ws + W2F_OFF);
  const bf16x8* cfG  = (const bf16x8*)(ws + CF_OFF);

  const int sg = blockIdx.x * 32 + sl;
  f32x4 y = *(const f32x4*)&x[sg * 64 + q * 4];
  float ld = ld_init[sg];
  const float dt = Tg[0] * 0.1f;                   // T / NUM_STEPS

  __syncthreads();

  auto dyn = [&](f32x4 yin, f32x4& dy, float& tr) {
    // stage input -> LDS (bf16)
    bf16x4 yb;
#pragma unroll
    for (int r = 0; r < 4; ++r) yb[r] = f2bf(yin[r]);
    *(bf16x4*)&ytL[sl * 88 + q * 4] = yb;
    __syncthreads();                               // B1: ytmp ready

    // ---- GEMM1: z1^T = W1 * ytmp^T  (K=64) -> h1, s1
    f32x4 a00 = {0,0,0,0}, a01 = {0,0,0,0}, a10 = {0,0,0,0}, a11 = {0,0,0,0};
#pragma unroll
    for (int kt = 0; kt < 2; ++kt) {
      bf16x8 A0 = *(const bf16x8*)&w1f[(((2 * wv + 0) * 2 + kt) * 64 + lane) * 8];
      bf16x8 A1 = *(const bf16x8*)&w1f[(((2 * wv + 1) * 2 + kt) * 64 + lane) * 8];
      bf16x8 B0 = *(const bf16x8*)&ytL[lm * 88 + kt * 32 + ko8];
      bf16x8 B1 = *(const bf16x8*)&ytL[(16 + lm) * 88 + kt * 32 + ko8];
      a00 = MFMA16(A0, B0, a00); a01 = MFMA16(A0, B1, a01);
      a10 = MFMA16(A1, B0, a10); a11 = MFMA16(A1, B1, a11);
    }
    {
      auto epi1 = [&](f32x4 z4, int r2, int c) {
        int row0 = (2 * wv + r2) * 16 + (lg << 2);
        int sc = c * 16 + lm;
        bf16x4 hh, ss;
#pragma unroll
        for (int r = 0; r < 4; ++r) {
          float h, s;
          sp_sig(z4[r] + b1L[row0 + r], h, s);
          hh[r] = f2bf(h); ss[r] = f2bf(s);
        }
        *(bf16x4*)&h1L[sc * 264 + row0] = hh;
        *(bf16x4*)&s1L_[sc * 264 + row0] = ss;
      };
      epi1(a00, 0, 0); epi1(a01, 0, 1); epi1(a10, 1, 0); epi1(a11, 1, 1);
    }
    __syncthreads();                               // B2: h1, s1 ready

    // ---- GEMM2: z2^T = W2 * h1^T (K=256) -> h2 (LDS), s2 (regs)
    f32x4 c00 = {0,0,0,0}, c01 = {0,0,0,0}, c10 = {0,0,0,0}, c11 = {0,0,0,0};
#pragma unroll
    for (int kt = 0; kt < 8; ++kt) {
      bf16x8 A0 = w2fG[((2 * wv + 0) * 8 + kt) * 64 + lane];
      bf16x8 A1 = w2fG[((2 * wv + 1) * 8 + kt) * 64 + lane];
      bf16x8 B0 = *(const bf16x8*)&h1L[lm * 264 + kt * 32 + ko8];
      bf16x8 B1 = *(const bf16x8*)&h1L[(16 + lm) * 264 + kt * 32 + ko8];
      c00 = MFMA16(A0, B0, c00); c01 = MFMA16(A0, B1, c01);
      c10 = MFMA16(A1, B0, c10); c11 = MFMA16(A1, B1, c11);
    }
    f32x4 s200, s201, s210, s211;
    {
      auto epi2 = [&](f32x4 z4, int r2, int c, f32x4& s2o) {
        int row0 = (2 * wv + r2) * 16 + (lg << 2);
        int sc = c * 16 + lm;
        bf16x4 hh;
#pragma unroll
        for (int r = 0; r < 4; ++r) {
          float h, s;
          sp_sig(z4[r] + b2L[row0 + r], h, s);
          hh[r] = f2bf(h); s2o[r] = s;
        }
        *(bf16x4*)&h2L[sc * 264 + row0] = hh;
      };
      epi2(c00, 0, 0, s200); epi2(c01, 0, 1, s201);
      epi2(c10, 1, 0, s210); epi2(c11, 1, 1, s211);
    }
    __syncthreads();                               // B3: h2 ready

    // ---- GEMMC: u^T = C * s1^T (K=256); trace partial = sum_k s2*u
    f32x4 u00 = {0,0,0,0}, u01 = {0,0,0,0}, u10 = {0,0,0,0}, u11 = {0,0,0,0};
#pragma unroll
    for (int kt = 0; kt < 8; ++kt) {
      bf16x8 A0 = cfG[((2 * wv + 0) * 8 + kt) * 64 + lane];
      bf16x8 A1 = cfG[((2 * wv + 1) * 8 + kt) * 64 + lane];
      bf16x8 B0 = *(const bf16x8*)&s1L_[lm * 264 + kt * 32 + ko8];
      bf16x8 B1 = *(const bf16x8*)&s1L_[(16 + lm) * 264 + kt * 32 + ko8];
      u00 = MFMA16(A0, B0, u00); u01 = MFMA16(A0, B1, u01);
      u10 = MFMA16(A1, B0, u10); u11 = MFMA16(A1, B1, u11);
    }
    float pl0 = 0.f, pl1 = 0.f;
#pragma unroll
    for (int r = 0; r < 4; ++r) {
      pl0 += u00[r] * s200[r] + u10[r] * s210[r];
      pl1 += u01[r] * s201[r] + u11[r] * s211[r];
    }
    pl0 += __shfl_xor(pl0, 16); pl0 += __shfl_xor(pl0, 32);
    pl1 += __shfl_xor(pl1, 16); pl1 += __shfl_xor(pl1, 32);
    if (lane < 16) { trP[wv][lane] = pl0; trP[wv][16 + lane] = pl1; }

    // ---- GEMM3: dy^T = W3 * h2^T (K=256), one 16x16 tile per wave
    f32x4 d3a = {0,0,0,0};
    const int m3 = wv & 3, c3 = wv >> 2;
#pragma unroll
    for (int kt = 0; kt < 8; ++kt) {
      bf16x8 A0 = *(const bf16x8*)&w3f[((m3 * 8 + kt) * 64 + lane) * 8];
      bf16x8 B0 = *(const bf16x8*)&h2L[(c3 * 16 + lm) * 264 + kt * 32 + ko8];
      d3a = MFMA16(A0, B0, d3a);
    }
    {
      int d0r = m3 * 16 + (lg << 2);
      int sc = c3 * 16 + lm;
      f32x4 dv;
#pragma unroll
      for (int r = 0; r < 4; ++r) dv[r] = d3a[r] + b3L[d0r + r];
      *(f32x4*)&dyL[sc * 68 + d0r] = dv;
    }
    __syncthreads();                               // B4: dy, trace ready

    dy = *(const f32x4*)&dyL[sl * 68 + q * 4];
    float t = 0.f;
#pragma unroll
    for (int w = 0; w < 8; ++w) t += trP[w][sl];
    tr = t;
  };

  // Dormand-Prince 5(4), fixed 10 steps
  const float A21 = 1.f / 5.f;
  const float A31 = 3.f / 40.f, A32 = 9.f / 40.f;
  const float A41 = 44.f / 45.f, A42 = -56.f / 15.f, A43 = 32.f / 9.f;
  const float A51 = 19372.f / 6561.f, A52 = -25360.f / 2187.f,
              A53 = 64448.f / 6561.f, A54 = -212.f / 729.f;
  const float A61 = 9017.f / 3168.f, A62 = -355.f / 33.f,
              A63 = 46732.f / 5247.f, A64 = 49.f / 176.f, A65 = -5103.f / 18656.f;
  const float C1 = 35.f / 384.f, C3 = 500.f / 1113.f, C4 = 125.f / 192.f,
              C5 = -2187.f / 6784.f, C6 = 11.f / 84.f;

  f32x4 k1, k2, k3, k4, k5, k6;
  float l1, l2, l3, l4, l5, l6;
#pragma unroll 1
  for (int step = 0; step < 10; ++step) {
    dyn(y, k1, l1);
    dyn(y + dt * (A21 * k1), k2, l2);
    dyn(y + dt * (A31 * k1 + A32 * k2), k3, l3);
    dyn(y + dt * (A41 * k1 + A42 * k2 + A43 * k3), k4, l4);
    dyn(y + dt * (A51 * k1 + A52 * k2 + A53 * k3 + A54 * k4), k5, l5);
    dyn(y + dt * (A61 * k1 + A62 * k2 + A63 * k3 + A64 * k4 + A65 * k5), k6, l6);
    y = y + dt * (C1 * k1 + C3 * k3 + C4 * k4 + C5 * k5 + C6 * k6);
    ld = ld + dt * (C1 * l1 + C3 * l3 + C4 * l4 + C5 * l5 + C6 * l6);
  }

  *(f32x4*)&outy[sg * 64 + q * 4] = y;
  if (q == 0) outl[sg] = ld;
}

extern "C" void kernel_launch(void* const* d_in, const int* in_sizes, int n_in,
                              void* d_out, int out_size, void* d_ws, size_t ws_size,
                              hipStream_t stream) {
  const float* x  = (const float*)d_in[0];
  const float* l0 = (const float*)d_in[1];
  const float* W1 = (const float*)d_in[2];
  const float* b1 = (const float*)d_in[3];
  const float* W2 = (const float*)d_in[4];
  const float* b2 = (const float*)d_in[5];
  const float* W3 = (const float*)d_in[6];
  const float* b3 = (const float*)d_in[7];
  const float* Tp = (const float*)d_in[8];
  short* ws = (short*)d_ws;

  cnf_prep<<<dim3(320), dim3(512), 0, stream>>>(W1, W2, W3, ws);

  float* outy = (float*)d_out;
  float* outl = outy + 8192 * 64;
  cnf_main<<<dim3(256), dim3(512), 0, stream>>>(x, l0, b1, b2, b3, Tp, ws, outy, outl);
}